// Round 6
// baseline (2854.452 us; speedup 1.0000x reference)
//
#include <hip/hip_runtime.h>
#include <hip/hip_fp16.h>
#include <math.h>

#define NN 100000
#define EE 3200000
#define EF 3300000
#define FE 7
#define SBS 7                       // log2(nodes per super-bucket)
#define SBN 128                     // nodes per super-bucket
#define NSB ((NN + SBN - 1) / SBN)  // 782 buckets
#define CHUNK 8192                  // edges per scatter workgroup

// ---------------- ws layout (bytes) ----------------
// 0     : double ea_sum[8]
// 64    : double bn_sum[32]
// 320   : double bn_sumsq[32]
// 576   : float  ea_mean[8]
// 608   : float  wend[32]
// 736   : float  c0
// 768   : int    sb_cnt[NSB]
// 4096  : int    sb_base[NSB+1]
// 8192  : int    sb_tail[NSB]
// 16384 : xl[NN*32] half, xr[NN*32] half, hb[NN*32] float
// then  : rec[EF*2] float4   ({src|dstLocal<<17, a0..a6} 32B, bucket-grouped)

__global__ void k_ea_sum(const float* __restrict__ ea, double* __restrict__ ea_sum) {
    float acc[FE];
#pragma unroll
    for (int f = 0; f < FE; ++f) acc[f] = 0.f;
    int stride = gridDim.x * blockDim.x;
    for (int e = blockIdx.x * blockDim.x + threadIdx.x; e < EE; e += stride) {
        const float* r = ea + (size_t)e * FE;
#pragma unroll
        for (int f = 0; f < FE; ++f) acc[f] += r[f];
    }
    __shared__ float part[4][FE];
    int wave = threadIdx.x >> 6;
#pragma unroll
    for (int f = 0; f < FE; ++f) {
        float v = acc[f];
        for (int o = 32; o > 0; o >>= 1) v += __shfl_down(v, o, 64);
        if ((threadIdx.x & 63) == 0) part[wave][f] = v;
    }
    __syncthreads();
    if (threadIdx.x < FE) {
        float s = part[0][threadIdx.x] + part[1][threadIdx.x] +
                  part[2][threadIdx.x] + part[3][threadIdx.x];
        atomicAdd(&ea_sum[threadIdx.x], (double)s);
    }
}

__global__ void k_ea_mean(const double* __restrict__ ea_sum, float* __restrict__ ea_mean) {
    int f = threadIdx.x;
    if (f < 8) ea_mean[f] = (f < FE) ? (float)(ea_sum[f] / (double)EE) : 0.f;
}

// per-bucket edge counts (LDS histogram -> one global atomic per block,bucket)
__global__ void k_hist(const int* __restrict__ ei, int* __restrict__ sb_cnt) {
    __shared__ int h[NSB];
    for (int i = threadIdx.x; i < NSB; i += blockDim.x) h[i] = 0;
    __syncthreads();
    int stride = gridDim.x * blockDim.x;
    for (int e = blockIdx.x * blockDim.x + threadIdx.x; e < EF; e += stride) {
        int d = (e < EE) ? ei[EE + e] : (e - EE);
        atomicAdd(&h[d >> SBS], 1);
    }
    __syncthreads();
    for (int i = threadIdx.x; i < NSB; i += blockDim.x)
        if (h[i]) atomicAdd(&sb_cnt[i], h[i]);
}

// exclusive scan of sb_cnt -> sb_base (+ sentinel), init sb_tail
__global__ void k_sbscan(const int* __restrict__ sb_cnt, int* __restrict__ sb_base,
                         int* __restrict__ sb_tail) {
    __shared__ int tmp[1024];
    int t = threadIdx.x;
    int c = (t < NSB) ? sb_cnt[t] : 0;
    tmp[t] = c;
    __syncthreads();
    for (int o = 1; o < 1024; o <<= 1) {
        int v = (t >= o) ? tmp[t - o] : 0;
        __syncthreads();
        tmp[t] += v;
        __syncthreads();
    }
    if (t < NSB) {
        int excl = tmp[t] - c;
        sb_base[t] = excl;
        sb_tail[t] = excl;
    }
    if (t == NSB) sb_base[NSB] = EF;
}

// bucket-grouped scatter: LDS count -> block reservation -> coalesced run writes
__global__ __launch_bounds__(256) void k_scatter(
    const int* __restrict__ ei, const float* __restrict__ ea,
    const float* __restrict__ ea_mean, int* __restrict__ sb_tail,
    float4* __restrict__ rec) {
    __shared__ int lc[NSB], lb[NSB];
    for (int i = threadIdx.x; i < NSB; i += blockDim.x) lc[i] = 0;
    int wgBase = blockIdx.x * CHUNK;
    __syncthreads();
#pragma unroll 4
    for (int k = 0; k < CHUNK / 256; ++k) {
        int e = wgBase + k * 256 + threadIdx.x;
        if (e < EF) {
            int d = (e < EE) ? ei[EE + e] : (e - EE);
            atomicAdd(&lc[d >> SBS], 1);
        }
    }
    __syncthreads();
    for (int i = threadIdx.x; i < NSB; i += blockDim.x) {
        int c = lc[i];
        lb[i] = c ? atomicAdd(&sb_tail[i], c) : 0;
        lc[i] = 0;
    }
    __syncthreads();
    for (int k = 0; k < CHUNK / 256; ++k) {
        int e = wgBase + k * 256 + threadIdx.x;
        if (e >= EF) continue;
        int d, s;
        float a[FE];
        if (e < EE) {
            d = ei[EE + e];
            s = ei[e];
            const float* r = ea + (size_t)e * FE;
#pragma unroll
            for (int f = 0; f < FE; ++f) a[f] = r[f];
        } else {
            d = e - EE;
            s = d;
#pragma unroll
            for (int f = 0; f < FE; ++f) a[f] = ea_mean[f];
        }
        int b = d >> SBS;
        int pos = lb[b] + atomicAdd(&lc[b], 1);
        unsigned w0 = (unsigned)s | ((unsigned)(d & (SBN - 1)) << 17);
        rec[(size_t)pos * 2]     = make_float4(__uint_as_float(w0), a[0], a[1], a[2]);
        rec[(size_t)pos * 2 + 1] = make_float4(a[3], a[4], a[5], a[6]);
    }
}

// xl = act(BN(h))@Wl+bl, xr = act(BN(h))@Wr+br, both stored fp16.
template <int FIN, bool BN>
__global__ void k_xform(const float* __restrict__ h,
                        const float* __restrict__ Wl, const float* __restrict__ bl,
                        const float* __restrict__ Wr, const float* __restrict__ br,
                        const double* __restrict__ bn_sum, const double* __restrict__ bn_sumsq,
                        const float* __restrict__ gamma, const float* __restrict__ beta,
                        __half* __restrict__ xl, __half* __restrict__ xr) {
    __shared__ float sWl[FIN * 32], sWr[FIN * 32], sb[64];
    __shared__ float smu[FIN], ssc[FIN], sbe[FIN];
    for (int i = threadIdx.x; i < FIN * 32; i += blockDim.x) { sWl[i] = Wl[i]; sWr[i] = Wr[i]; }
    if (threadIdx.x < 32) { sb[threadIdx.x] = bl[threadIdx.x]; sb[32 + threadIdx.x] = br[threadIdx.x]; }
    if (BN && threadIdx.x < FIN) {
        int f = threadIdx.x;
        double mu = bn_sum[f] * (1.0 / NN);
        double var = bn_sumsq[f] * (1.0 / NN) - mu * mu;
        smu[f] = (float)mu;
        ssc[f] = gamma[f] * (float)(1.0 / sqrt(var + 1e-5));
        sbe[f] = beta[f];
    }
    __syncthreads();
    int idx = blockIdx.x * blockDim.x + threadIdx.x;
    if (idx >= NN * 32) return;
    int n = idx >> 5, c = idx & 31;
    const float* hr = h + (size_t)n * FIN;
    float al = sb[c], ar = sb[32 + c];
#pragma unroll
    for (int f = 0; f < FIN; ++f) {
        float v = hr[f];
        if (BN) {
            v = fmaf(v - smu[f], ssc[f], sbe[f]);
            v = v > 0.f ? v : 0.01f * v;
        }
        al = fmaf(v, sWl[f * 32 + c], al);
        ar = fmaf(v, sWr[f * 32 + c], ar);
    }
    xl[idx] = __float2half(al);
    xr[idx] = __float2half(ar);
}

// GATv2 per super-bucket: sequential record read, swizzled-LDS atomic aggregation.
// 8 lanes per edge, 4 channels per lane; no-max softmax (logits bounded).
__global__ __launch_bounds__(256) void k_gat_b(
    const int* __restrict__ sb_base, const float4* __restrict__ rec,
    const __half* __restrict__ xl, const __half* __restrict__ xr,
    const float* __restrict__ We, const float* __restrict__ att,
    const float* __restrict__ bias, float* __restrict__ hout) {
    __shared__ float acc[SBN * 32];  // acc[n][(c+n)&31]
    __shared__ float den[SBN * 4];   // den[n][(h+n)&3]
    for (int i = threadIdx.x; i < SBN * 32; i += 256) acc[i] = 0.f;
    for (int i = threadIdx.x; i < SBN * 4; i += 256) den[i] = 0.f;

    int c0 = (threadIdx.x & 7) * 4;
    float we[FE][4];
#pragma unroll
    for (int f = 0; f < FE; ++f)
#pragma unroll
        for (int j = 0; j < 4; ++j) we[f][j] = We[f * 32 + c0 + j];
    float at0 = att[c0], at1 = att[c0 + 1], at2 = att[c0 + 2], at3 = att[c0 + 3];

    int sb = blockIdx.x;
    int nodeBase = sb << SBS;
    int start = sb_base[sb], end = sb_base[sb + 1];
    __syncthreads();

    for (int p = start + (threadIdx.x >> 3); p < end; p += 32) {
        float4 r0 = rec[(size_t)p * 2];
        float4 r1 = rec[(size_t)p * 2 + 1];
        unsigned w0 = __float_as_uint(r0.x);
        int src = (int)(w0 & 0x1FFFFu);
        int dl  = (int)(w0 >> 17);

        float2 rawl = *(const float2*)(xl + (size_t)src * 32 + c0);
        float2 rawr = *(const float2*)(xr + (size_t)(nodeBase + dl) * 32 + c0);
        float2 l01 = __half22float2(*(const __half2*)&rawl.x);
        float2 l23 = __half22float2(*(const __half2*)&rawl.y);
        float2 q01 = __half22float2(*(const __half2*)&rawr.x);
        float2 q23 = __half22float2(*(const __half2*)&rawr.y);

        float ee0, ee1, ee2, ee3;
        ee0 = r0.y * we[0][0]; ee1 = r0.y * we[0][1]; ee2 = r0.y * we[0][2]; ee3 = r0.y * we[0][3];
        ee0 = fmaf(r0.z, we[1][0], ee0); ee1 = fmaf(r0.z, we[1][1], ee1);
        ee2 = fmaf(r0.z, we[1][2], ee2); ee3 = fmaf(r0.z, we[1][3], ee3);
        ee0 = fmaf(r0.w, we[2][0], ee0); ee1 = fmaf(r0.w, we[2][1], ee1);
        ee2 = fmaf(r0.w, we[2][2], ee2); ee3 = fmaf(r0.w, we[2][3], ee3);
        ee0 = fmaf(r1.x, we[3][0], ee0); ee1 = fmaf(r1.x, we[3][1], ee1);
        ee2 = fmaf(r1.x, we[3][2], ee2); ee3 = fmaf(r1.x, we[3][3], ee3);
        ee0 = fmaf(r1.y, we[4][0], ee0); ee1 = fmaf(r1.y, we[4][1], ee1);
        ee2 = fmaf(r1.y, we[4][2], ee2); ee3 = fmaf(r1.y, we[4][3], ee3);
        ee0 = fmaf(r1.z, we[5][0], ee0); ee1 = fmaf(r1.z, we[5][1], ee1);
        ee2 = fmaf(r1.z, we[5][2], ee2); ee3 = fmaf(r1.z, we[5][3], ee3);
        ee0 = fmaf(r1.w, we[6][0], ee0); ee1 = fmaf(r1.w, we[6][1], ee1);
        ee2 = fmaf(r1.w, we[6][2], ee2); ee3 = fmaf(r1.w, we[6][3], ee3);

        float v0 = l01.x + q01.x + ee0;
        float v1 = l01.y + q01.y + ee1;
        float v2 = l23.x + q23.x + ee2;
        float v3 = l23.y + q23.y + ee3;
        v0 = v0 > 0.f ? v0 : 0.2f * v0;
        v1 = v1 > 0.f ? v1 : 0.2f * v1;
        v2 = v2 > 0.f ? v2 : 0.2f * v2;
        v3 = v3 > 0.f ? v3 : 0.2f * v3;
        float pl = fmaf(v0, at0, fmaf(v1, at1, fmaf(v2, at2, v3 * at3)));
        float L = pl + __shfl_xor(pl, 1, 64);  // full head logit (pair lanes same edge)
        float ex = __expf(L);

        int ab = dl * 32;
        atomicAdd(&acc[ab + ((c0 + 0 + dl) & 31)], ex * l01.x);
        atomicAdd(&acc[ab + ((c0 + 1 + dl) & 31)], ex * l01.y);
        atomicAdd(&acc[ab + ((c0 + 2 + dl) & 31)], ex * l23.x);
        atomicAdd(&acc[ab + ((c0 + 3 + dl) & 31)], ex * l23.y);
        if ((threadIdx.x & 1) == 0)
            atomicAdd(&den[dl * 4 + (((c0 >> 3) + dl) & 3)], ex);
    }
    __syncthreads();

    int nNodes = NN - nodeBase;
    if (nNodes > SBN) nNodes = SBN;
    int lim = nNodes * 32;
    for (int i = threadIdx.x; i < lim; i += 256) {
        int n = i >> 5, s = i & 31;
        int c = (s - n) & 31;
        float dv = den[n * 4 + (((c >> 3) + n) & 3)];
        float o = acc[i] / (dv + 1e-16f) + bias[c];
        hout[(size_t)(nodeBase + n) * 32 + c] = o;
    }
}

__global__ void k_bn_stats(const float* __restrict__ h, double* __restrict__ bn_sum,
                           double* __restrict__ bn_sumsq) {
    int c = threadIdx.x & 31;
    int row0 = (blockIdx.x * blockDim.x + threadIdx.x) >> 5;
    int rstride = (gridDim.x * blockDim.x) >> 5;
    float s = 0.f, s2 = 0.f;
    for (int n = row0; n < NN; n += rstride) {
        float v = h[(size_t)n * 32 + c];
        s += v;
        s2 = fmaf(v, v, s2);
    }
    s += __shfl_down(s, 32, 64);
    s2 += __shfl_down(s2, 32, 64);
    __shared__ float ls[4][32], ls2[4][32];
    int w = threadIdx.x >> 6;
    if ((threadIdx.x & 63) < 32) { ls[w][c] = s; ls2[w][c] = s2; }
    __syncthreads();
    if (threadIdx.x < 32) {
        float tsum = 0.f, tsq = 0.f;
        for (int i = 0; i < 4; ++i) { tsum += ls[i][threadIdx.x]; tsq += ls2[i][threadIdx.x]; }
        atomicAdd(&bn_sum[threadIdx.x], (double)tsum);
        atomicAdd(&bn_sumsq[threadIdx.x], (double)tsq);
    }
}

// wend = Wreg@Wend, c0 = breg.Wend + bend  (linear∘linear collapse)
__global__ void k_wend(const float* __restrict__ Wreg, const float* __restrict__ breg,
                       const float* __restrict__ Wend, const float* __restrict__ bend,
                       float* __restrict__ wend, float* __restrict__ c0v) {
    int t = threadIdx.x;
    if (t < 32) {
        float s = 0.f;
        for (int k = 0; k < 500; ++k) s = fmaf(Wreg[t * 500 + k], Wend[k], s);
        wend[t] = s;
    } else if (t == 32) {
        float s = 0.f;
        for (int k = 0; k < 500; ++k) s = fmaf(breg[k], Wend[k], s);
        *c0v = s + bend[0];
    }
}

__global__ void k_out(const float* __restrict__ h, const float* __restrict__ wend,
                      const float* __restrict__ c0v, float* __restrict__ out) {
    int n = blockIdx.x * blockDim.x + threadIdx.x;
    if (n >= NN) return;
    const float* r = h + (size_t)n * 32;
    float s = *c0v;
#pragma unroll
    for (int c = 0; c < 32; ++c) {
        float v = r[c];
        v = v > 0.f ? v : 0.01f * v;
        s = fmaf(v, wend[c], s);
    }
    out[n] = s;
}

extern "C" void kernel_launch(void* const* d_in, const int* in_sizes, int n_in,
                              void* d_out, int out_size, void* d_ws, size_t ws_size,
                              hipStream_t stream) {
    (void)in_sizes; (void)n_in; (void)out_size; (void)ws_size;
    const float* x    = (const float*)d_in[0];
    const int*   ei   = (const int*)d_in[1];
    const float* ea   = (const float*)d_in[2];
    const float* Wl1  = (const float*)d_in[3];
    const float* bl1  = (const float*)d_in[4];
    const float* Wr1  = (const float*)d_in[5];
    const float* br1  = (const float*)d_in[6];
    const float* We1  = (const float*)d_in[7];
    const float* att1 = (const float*)d_in[8];
    const float* b1   = (const float*)d_in[9];
    const float* Wl2  = (const float*)d_in[10];
    const float* bl2  = (const float*)d_in[11];
    const float* Wr2  = (const float*)d_in[12];
    const float* br2  = (const float*)d_in[13];
    const float* We2  = (const float*)d_in[14];
    const float* att2 = (const float*)d_in[15];
    const float* b2   = (const float*)d_in[16];
    const float* gamma= (const float*)d_in[17];
    const float* beta = (const float*)d_in[18];
    const float* Wreg = (const float*)d_in[19];
    const float* breg = (const float*)d_in[20];
    const float* Wend = (const float*)d_in[21];
    const float* bend = (const float*)d_in[22];
    float* out = (float*)d_out;

    char* w = (char*)d_ws;
    double* ea_sum   = (double*)(w + 0);
    double* bn_sum   = (double*)(w + 64);
    double* bn_sumsq = (double*)(w + 320);
    float*  ea_mean  = (float*)(w + 576);
    float*  wend     = (float*)(w + 608);
    float*  c0v      = (float*)(w + 736);
    int*    sb_cnt   = (int*)(w + 768);
    int*    sb_base  = (int*)(w + 4096);
    int*    sb_tail  = (int*)(w + 8192);
    size_t o = 16384;
    __half* xl = (__half*)(w + o); o += ((size_t)NN * 32 * 2 + 255) & ~(size_t)255;
    __half* xr = (__half*)(w + o); o += ((size_t)NN * 32 * 2 + 255) & ~(size_t)255;
    float* hb = (float*)(w + o); o += (size_t)NN * 32 * 4;
    float4* rec = (float4*)(w + o); o += (size_t)EF * 32;

    hipMemsetAsync(w, 0, 16384, stream);

    k_ea_sum<<<256, 256, 0, stream>>>(ea, ea_sum);
    k_ea_mean<<<1, 64, 0, stream>>>(ea_sum, ea_mean);
    k_hist<<<1024, 256, 0, stream>>>(ei, sb_cnt);
    k_sbscan<<<1, 1024, 0, stream>>>(sb_cnt, sb_base, sb_tail);
    k_scatter<<<(EF + CHUNK - 1) / CHUNK, 256, 0, stream>>>(ei, ea, ea_mean, sb_tail, rec);
    k_wend<<<1, 64, 0, stream>>>(Wreg, breg, Wend, bend, wend, c0v);

    const int xbl = (NN * 32 + 255) / 256;

    // layer 1 (no BN on raw input x)
    k_xform<2, false><<<xbl, 256, 0, stream>>>(x, Wl1, bl1, Wr1, br1,
                                               bn_sum, bn_sumsq, gamma, beta, xl, xr);
    k_gat_b<<<NSB, 256, 0, stream>>>(sb_base, rec, xl, xr, We1, att1, b1, hb);

    // 2x (BN-stats -> fused BN+lrelu+xform -> layer2 GAT)
    for (int it = 0; it < 2; ++it) {
        hipMemsetAsync(w + 64, 0, 512, stream);
        k_bn_stats<<<256, 256, 0, stream>>>(hb, bn_sum, bn_sumsq);
        k_xform<32, true><<<xbl, 256, 0, stream>>>(hb, Wl2, bl2, Wr2, br2,
                                                   bn_sum, bn_sumsq, gamma, beta, xl, xr);
        k_gat_b<<<NSB, 256, 0, stream>>>(sb_base, rec, xl, xr, We2, att2, b2, hb);
    }

    k_out<<<(NN + 255) / 256, 256, 0, stream>>>(hb, wend, c0v, out);
}

// Round 7
// 1253.444 us; speedup vs baseline: 2.2773x; 2.2773x over previous
//
#include <hip/hip_runtime.h>
#include <hip/hip_fp16.h>
#include <math.h>

#define NN 100000
#define EE 3200000
#define EF 3300000
#define FE 7
#define GNB 32    // nodes per k_gat block (3125 blocks exactly)
#define CR 512    // records staged per chunk (16KB LDS)
#define NPASS 4   // k_fill dst-range passes (write region ~26MB/pass -> L2 merge)

// ---------------- ws layout ----------------
// header: ea_sum/bn_sum/bn_sumsq/ea_mean/wend/c0 (1024B)
// offs[NN]; xl[NN*32] half; xr[NN*32] half; hb[NN*32] float; rec[EF*2] float4

__global__ void k_ea_sum(const float* __restrict__ ea, double* __restrict__ ea_sum) {
    float acc[FE];
#pragma unroll
    for (int f = 0; f < FE; ++f) acc[f] = 0.f;
    int stride = gridDim.x * blockDim.x;
    for (int e = blockIdx.x * blockDim.x + threadIdx.x; e < EE; e += stride) {
        const float* r = ea + (size_t)e * FE;
#pragma unroll
        for (int f = 0; f < FE; ++f) acc[f] += r[f];
    }
    __shared__ float part[4][FE];
    int wave = threadIdx.x >> 6;
#pragma unroll
    for (int f = 0; f < FE; ++f) {
        float v = acc[f];
        for (int o = 32; o > 0; o >>= 1) v += __shfl_down(v, o, 64);
        if ((threadIdx.x & 63) == 0) part[wave][f] = v;
    }
    __syncthreads();
    if (threadIdx.x < FE) {
        float s = part[0][threadIdx.x] + part[1][threadIdx.x] +
                  part[2][threadIdx.x] + part[3][threadIdx.x];
        atomicAdd(&ea_sum[threadIdx.x], (double)s);
    }
}

__global__ void k_ea_mean(const double* __restrict__ ea_sum, float* __restrict__ ea_mean) {
    int f = threadIdx.x;
    if (f < 8) ea_mean[f] = (f < FE) ? (float)(ea_sum[f] / (double)EE) : 0.f;
}

__global__ void k_degree(const int* __restrict__ ei, int* __restrict__ offs) {
    int e = blockIdx.x * blockDim.x + threadIdx.x;
    if (e >= EF) return;
    int d = (e < EE) ? ei[EE + e] : (e - EE);
    atomicAdd(&offs[d], 1);
}

// single-workgroup in-place exclusive scan of offs[NN]
__global__ void k_scan(int* __restrict__ offs) {
    __shared__ int part[1024];
    int t = threadIdx.x;
    const int chunk = (NN + 1023) / 1024;
    int b = t * chunk;
    int e = b + chunk; if (e > NN) e = NN;
    int s = 0;
    for (int i = b; i < e; ++i) s += offs[i];
    part[t] = s;
    __syncthreads();
    for (int o = 1; o < 1024; o <<= 1) {
        int v = (t >= o) ? part[t - o] : 0;
        __syncthreads();
        part[t] += v;
        __syncthreads();
    }
    int run = (t > 0) ? part[t - 1] : 0;
    for (int i = b; i < e; ++i) { int d = offs[i]; offs[i] = run; run += d; }
}

// dst-range pass scatter: writes confined to a ~26MB rec region -> L2 merges lines
__global__ void k_fill(const int* __restrict__ ei, const float* __restrict__ ea,
                       const float* __restrict__ ea_mean, int* __restrict__ offs,
                       float4* __restrict__ rec, int dlo, int dhi) {
    int e = blockIdx.x * blockDim.x + threadIdx.x;
    if (e >= EF) return;
    int d = (e < EE) ? ei[EE + e] : (e - EE);
    if (d < dlo || d >= dhi) return;
    int pos = atomicAdd(&offs[d], 1);
    float a[FE];
    int s;
    if (e < EE) {
        s = ei[e];
        const float* r = ea + (size_t)e * FE;
#pragma unroll
        for (int f = 0; f < FE; ++f) a[f] = r[f];
    } else {
        s = e - EE;
#pragma unroll
        for (int f = 0; f < FE; ++f) a[f] = ea_mean[f];
    }
    rec[(size_t)pos * 2]     = make_float4(__int_as_float(s), a[0], a[1], a[2]);
    rec[(size_t)pos * 2 + 1] = make_float4(a[3], a[4], a[5], a[6]);
}

// xl = act(BN(h))@Wl+bl, xr = act(BN(h))@Wr+br, both stored fp16.
template <int FIN, bool BN>
__global__ void k_xform(const float* __restrict__ h,
                        const float* __restrict__ Wl, const float* __restrict__ bl,
                        const float* __restrict__ Wr, const float* __restrict__ br,
                        const double* __restrict__ bn_sum, const double* __restrict__ bn_sumsq,
                        const float* __restrict__ gamma, const float* __restrict__ beta,
                        __half* __restrict__ xl, __half* __restrict__ xr) {
    __shared__ float sWl[FIN * 32], sWr[FIN * 32], sb[64];
    __shared__ float smu[FIN], ssc[FIN], sbe[FIN];
    for (int i = threadIdx.x; i < FIN * 32; i += blockDim.x) { sWl[i] = Wl[i]; sWr[i] = Wr[i]; }
    if (threadIdx.x < 32) { sb[threadIdx.x] = bl[threadIdx.x]; sb[32 + threadIdx.x] = br[threadIdx.x]; }
    if (BN && threadIdx.x < FIN) {
        int f = threadIdx.x;
        double mu = bn_sum[f] * (1.0 / NN);
        double var = bn_sumsq[f] * (1.0 / NN) - mu * mu;
        smu[f] = (float)mu;
        ssc[f] = gamma[f] * (float)(1.0 / sqrt(var + 1e-5));
        sbe[f] = beta[f];
    }
    __syncthreads();
    int idx = blockIdx.x * blockDim.x + threadIdx.x;
    if (idx >= NN * 32) return;
    int n = idx >> 5, c = idx & 31;
    const float* hr = h + (size_t)n * FIN;
    float al = sb[c], ar = sb[32 + c];
#pragma unroll
    for (int f = 0; f < FIN; ++f) {
        float v = hr[f];
        if (BN) {
            v = fmaf(v - smu[f], ssc[f], sbe[f]);
            v = v > 0.f ? v : 0.01f * v;
        }
        al = fmaf(v, sWl[f * 32 + c], al);
        ar = fmaf(v, sWr[f * 32 + c], ar);
    }
    xl[idx] = __float2half(al);
    xr[idx] = __float2half(ar);
}

// GATv2, block-tiled: 32 consecutive dst nodes per block; their contiguous CSR
// slice is staged through LDS in coalesced 16KB chunks (one sequential global
// stream instead of 64 interleaved streams/wave). 8 lanes per node, 4 ch/lane,
// register accumulation, no-max softmax (logits bounded, shift-invariant).
__global__ __launch_bounds__(256) void k_gat_t(
    const int* __restrict__ offs, const float4* __restrict__ rec,
    const __half* __restrict__ xl, const __half* __restrict__ xr,
    const float* __restrict__ We, const float* __restrict__ att,
    const float* __restrict__ bias, float* __restrict__ hout) {
    __shared__ float4 srec[CR * 2];
    int n0 = blockIdx.x * GNB;
    int g = threadIdx.x >> 3, j = threadIdx.x & 7, c0 = j * 4;
    int node = n0 + g;

    float we[FE][4];
#pragma unroll
    for (int f = 0; f < FE; ++f)
#pragma unroll
        for (int k = 0; k < 4; ++k) we[f][k] = We[f * 32 + c0 + k];
    float at0 = att[c0], at1 = att[c0 + 1], at2 = att[c0 + 2], at3 = att[c0 + 3];

    float2 rawr = *(const float2*)(xr + (size_t)node * 32 + c0);
    float2 q01 = __half22float2(*(const __half2*)&rawr.x);
    float2 q23 = __half22float2(*(const __half2*)&rawr.y);

    int s_g = (node == 0) ? 0 : offs[node - 1];
    int e_g = offs[node];
    int range0 = (n0 == 0) ? 0 : offs[n0 - 1];
    int range1 = offs[n0 + GNB - 1];

    float sm = 0.f, acc0 = 0.f, acc1 = 0.f, acc2 = 0.f, acc3 = 0.f;

    for (int base = range0; base < range1; base += CR) {
        int cnt = range1 - base; if (cnt > CR) cnt = CR;
        __syncthreads();
        for (int i = threadIdx.x; i < cnt * 2; i += 256)
            srec[i] = rec[(size_t)base * 2 + i];
        __syncthreads();
        int lo = s_g > base ? s_g : base;
        int hi = e_g < base + cnt ? e_g : base + cnt;
        for (int p = lo; p < hi; ++p) {
            float4 r0 = srec[(p - base) * 2];
            float4 r1 = srec[(p - base) * 2 + 1];
            int src = __float_as_int(r0.x);
            float2 rawl = *(const float2*)(xl + (size_t)src * 32 + c0);
            float2 l01 = __half22float2(*(const __half2*)&rawl.x);
            float2 l23 = __half22float2(*(const __half2*)&rawl.y);

            float ee0, ee1, ee2, ee3;
            ee0 = r0.y * we[0][0]; ee1 = r0.y * we[0][1]; ee2 = r0.y * we[0][2]; ee3 = r0.y * we[0][3];
            ee0 = fmaf(r0.z, we[1][0], ee0); ee1 = fmaf(r0.z, we[1][1], ee1);
            ee2 = fmaf(r0.z, we[1][2], ee2); ee3 = fmaf(r0.z, we[1][3], ee3);
            ee0 = fmaf(r0.w, we[2][0], ee0); ee1 = fmaf(r0.w, we[2][1], ee1);
            ee2 = fmaf(r0.w, we[2][2], ee2); ee3 = fmaf(r0.w, we[2][3], ee3);
            ee0 = fmaf(r1.x, we[3][0], ee0); ee1 = fmaf(r1.x, we[3][1], ee1);
            ee2 = fmaf(r1.x, we[3][2], ee2); ee3 = fmaf(r1.x, we[3][3], ee3);
            ee0 = fmaf(r1.y, we[4][0], ee0); ee1 = fmaf(r1.y, we[4][1], ee1);
            ee2 = fmaf(r1.y, we[4][2], ee2); ee3 = fmaf(r1.y, we[4][3], ee3);
            ee0 = fmaf(r1.z, we[5][0], ee0); ee1 = fmaf(r1.z, we[5][1], ee1);
            ee2 = fmaf(r1.z, we[5][2], ee2); ee3 = fmaf(r1.z, we[5][3], ee3);
            ee0 = fmaf(r1.w, we[6][0], ee0); ee1 = fmaf(r1.w, we[6][1], ee1);
            ee2 = fmaf(r1.w, we[6][2], ee2); ee3 = fmaf(r1.w, we[6][3], ee3);

            float v0 = l01.x + q01.x + ee0;
            float v1 = l01.y + q01.y + ee1;
            float v2 = l23.x + q23.x + ee2;
            float v3 = l23.y + q23.y + ee3;
            v0 = v0 > 0.f ? v0 : 0.2f * v0;
            v1 = v1 > 0.f ? v1 : 0.2f * v1;
            v2 = v2 > 0.f ? v2 : 0.2f * v2;
            v3 = v3 > 0.f ? v3 : 0.2f * v3;
            float pl = fmaf(v0, at0, fmaf(v1, at1, fmaf(v2, at2, v3 * at3)));
            float L = pl + __shfl_xor(pl, 1, 64);  // per-head logit (pair lanes)
            float ex = __expf(L);
            sm += ex;
            acc0 = fmaf(ex, l01.x, acc0);
            acc1 = fmaf(ex, l01.y, acc1);
            acc2 = fmaf(ex, l23.x, acc2);
            acc3 = fmaf(ex, l23.y, acc3);
        }
    }
    float inv = 1.f / (sm + 1e-16f);
    float4 o;
    o.x = fmaf(acc0, inv, bias[c0 + 0]);
    o.y = fmaf(acc1, inv, bias[c0 + 1]);
    o.z = fmaf(acc2, inv, bias[c0 + 2]);
    o.w = fmaf(acc3, inv, bias[c0 + 3]);
    *(float4*)(hout + (size_t)node * 32 + c0) = o;
}

__global__ void k_bn_stats(const float* __restrict__ h, double* __restrict__ bn_sum,
                           double* __restrict__ bn_sumsq) {
    int c = threadIdx.x & 31;
    int row0 = (blockIdx.x * blockDim.x + threadIdx.x) >> 5;
    int rstride = (gridDim.x * blockDim.x) >> 5;
    float s = 0.f, s2 = 0.f;
    for (int n = row0; n < NN; n += rstride) {
        float v = h[(size_t)n * 32 + c];
        s += v;
        s2 = fmaf(v, v, s2);
    }
    s += __shfl_down(s, 32, 64);
    s2 += __shfl_down(s2, 32, 64);
    __shared__ float ls[4][32], ls2[4][32];
    int w = threadIdx.x >> 6;
    if ((threadIdx.x & 63) < 32) { ls[w][c] = s; ls2[w][c] = s2; }
    __syncthreads();
    if (threadIdx.x < 32) {
        float tsum = 0.f, tsq = 0.f;
        for (int i = 0; i < 4; ++i) { tsum += ls[i][threadIdx.x]; tsq += ls2[i][threadIdx.x]; }
        atomicAdd(&bn_sum[threadIdx.x], (double)tsum);
        atomicAdd(&bn_sumsq[threadIdx.x], (double)tsq);
    }
}

// wend = Wreg@Wend, c0 = breg.Wend + bend  (linear∘linear collapse)
__global__ void k_wend(const float* __restrict__ Wreg, const float* __restrict__ breg,
                       const float* __restrict__ Wend, const float* __restrict__ bend,
                       float* __restrict__ wend, float* __restrict__ c0v) {
    int t = threadIdx.x;
    if (t < 32) {
        float s = 0.f;
        for (int k = 0; k < 500; ++k) s = fmaf(Wreg[t * 500 + k], Wend[k], s);
        wend[t] = s;
    } else if (t == 32) {
        float s = 0.f;
        for (int k = 0; k < 500; ++k) s = fmaf(breg[k], Wend[k], s);
        *c0v = s + bend[0];
    }
}

__global__ void k_out(const float* __restrict__ h, const float* __restrict__ wend,
                      const float* __restrict__ c0v, float* __restrict__ out) {
    int n = blockIdx.x * blockDim.x + threadIdx.x;
    if (n >= NN) return;
    const float* r = h + (size_t)n * 32;
    float s = *c0v;
#pragma unroll
    for (int c = 0; c < 32; ++c) {
        float v = r[c];
        v = v > 0.f ? v : 0.01f * v;
        s = fmaf(v, wend[c], s);
    }
    out[n] = s;
}

extern "C" void kernel_launch(void* const* d_in, const int* in_sizes, int n_in,
                              void* d_out, int out_size, void* d_ws, size_t ws_size,
                              hipStream_t stream) {
    (void)in_sizes; (void)n_in; (void)out_size; (void)ws_size;
    const float* x    = (const float*)d_in[0];
    const int*   ei   = (const int*)d_in[1];
    const float* ea   = (const float*)d_in[2];
    const float* Wl1  = (const float*)d_in[3];
    const float* bl1  = (const float*)d_in[4];
    const float* Wr1  = (const float*)d_in[5];
    const float* br1  = (const float*)d_in[6];
    const float* We1  = (const float*)d_in[7];
    const float* att1 = (const float*)d_in[8];
    const float* b1   = (const float*)d_in[9];
    const float* Wl2  = (const float*)d_in[10];
    const float* bl2  = (const float*)d_in[11];
    const float* Wr2  = (const float*)d_in[12];
    const float* br2  = (const float*)d_in[13];
    const float* We2  = (const float*)d_in[14];
    const float* att2 = (const float*)d_in[15];
    const float* b2   = (const float*)d_in[16];
    const float* gamma= (const float*)d_in[17];
    const float* beta = (const float*)d_in[18];
    const float* Wreg = (const float*)d_in[19];
    const float* breg = (const float*)d_in[20];
    const float* Wend = (const float*)d_in[21];
    const float* bend = (const float*)d_in[22];
    float* out = (float*)d_out;

    char* w = (char*)d_ws;
    double* ea_sum   = (double*)(w + 0);
    double* bn_sum   = (double*)(w + 64);
    double* bn_sumsq = (double*)(w + 320);
    float*  ea_mean  = (float*)(w + 576);
    float*  wend     = (float*)(w + 608);
    float*  c0v      = (float*)(w + 736);
    size_t o = 1024;
    int* offs = (int*)(w + o); o += ((size_t)NN * 4 + 255) & ~(size_t)255;
    __half* xl = (__half*)(w + o); o += ((size_t)NN * 32 * 2 + 255) & ~(size_t)255;
    __half* xr = (__half*)(w + o); o += ((size_t)NN * 32 * 2 + 255) & ~(size_t)255;
    float* hb = (float*)(w + o); o += (size_t)NN * 32 * 4;
    float4* rec = (float4*)(w + o); o += (size_t)EF * 32;

    hipMemsetAsync(w, 0, 1024, stream);
    hipMemsetAsync(offs, 0, (size_t)NN * 4, stream);

    const int ebl = (EF + 255) / 256;
    k_ea_sum<<<256, 256, 0, stream>>>(ea, ea_sum);
    k_ea_mean<<<1, 64, 0, stream>>>(ea_sum, ea_mean);
    k_degree<<<ebl, 256, 0, stream>>>(ei, offs);
    k_scan<<<1, 1024, 0, stream>>>(offs);
    for (int p = 0; p < NPASS; ++p) {
        int dlo = (NN * p) / NPASS, dhi = (NN * (p + 1)) / NPASS;
        k_fill<<<ebl, 256, 0, stream>>>(ei, ea, ea_mean, offs, rec, dlo, dhi);
    }
    k_wend<<<1, 64, 0, stream>>>(Wreg, breg, Wend, bend, wend, c0v);

    const int xbl = (NN * 32 + 255) / 256;
    const int gbl = NN / GNB;  // 3125, exact

    // layer 1 (no BN on raw input x)
    k_xform<2, false><<<xbl, 256, 0, stream>>>(x, Wl1, bl1, Wr1, br1,
                                               bn_sum, bn_sumsq, gamma, beta, xl, xr);
    k_gat_t<<<gbl, 256, 0, stream>>>(offs, rec, xl, xr, We1, att1, b1, hb);

    // 2x (BN-stats -> fused BN+lrelu+xform -> layer2 GAT)
    for (int it = 0; it < 2; ++it) {
        hipMemsetAsync(w + 64, 0, 512, stream);
        k_bn_stats<<<256, 256, 0, stream>>>(hb, bn_sum, bn_sumsq);
        k_xform<32, true><<<xbl, 256, 0, stream>>>(hb, Wl2, bl2, Wr2, br2,
                                                   bn_sum, bn_sumsq, gamma, beta, xl, xr);
        k_gat_t<<<gbl, 256, 0, stream>>>(offs, rec, xl, xr, We2, att2, b2, hb);
    }

    k_out<<<(NN + 255) / 256, 256, 0, stream>>>(hb, wend, c0v, out);
}

// Round 8
// 1050.832 us; speedup vs baseline: 2.7164x; 1.1928x over previous
//
#include <hip/hip_runtime.h>
#include <hip/hip_fp16.h>
#include <math.h>

#define NN 100000
#define EE 3200000
#define EF 3300000
#define FE 7
#define GNB 32    // nodes per k_gat block (3125 blocks exactly)
#define CR 512    // records staged per chunk (16KB LDS)
#define SCB 1024  // elements per scan block
#define SNB ((NN + SCB - 1) / SCB)  // 98 scan blocks

// ---------------- ws layout ----------------
// header: ea_sum/bn_sum/bn_sumsq/ea_mean/wend/c0 (1024B) ; scan_sums[128] @1024
// offs[NN]; xl[NN*32] half; xr[NN*32] half; hb[NN*32] float; rec[EF*2] float4

__global__ void k_ea_sum(const float* __restrict__ ea, double* __restrict__ ea_sum) {
    float acc[FE];
#pragma unroll
    for (int f = 0; f < FE; ++f) acc[f] = 0.f;
    int stride = gridDim.x * blockDim.x;
    for (int e = blockIdx.x * blockDim.x + threadIdx.x; e < EE; e += stride) {
        const float* r = ea + (size_t)e * FE;
#pragma unroll
        for (int f = 0; f < FE; ++f) acc[f] += r[f];
    }
    __shared__ float part[4][FE];
    int wave = threadIdx.x >> 6;
#pragma unroll
    for (int f = 0; f < FE; ++f) {
        float v = acc[f];
        for (int o = 32; o > 0; o >>= 1) v += __shfl_down(v, o, 64);
        if ((threadIdx.x & 63) == 0) part[wave][f] = v;
    }
    __syncthreads();
    if (threadIdx.x < FE) {
        float s = part[0][threadIdx.x] + part[1][threadIdx.x] +
                  part[2][threadIdx.x] + part[3][threadIdx.x];
        atomicAdd(&ea_sum[threadIdx.x], (double)s);
    }
}

__global__ void k_ea_mean(const double* __restrict__ ea_sum, float* __restrict__ ea_mean) {
    int f = threadIdx.x;
    if (f < 8) ea_mean[f] = (f < FE) ? (float)(ea_sum[f] / (double)EE) : 0.f;
}

__global__ void k_degree(const int* __restrict__ ei, int* __restrict__ offs) {
    int e = blockIdx.x * blockDim.x + threadIdx.x;
    if (e >= EF) return;
    int d = (e < EE) ? ei[EE + e] : (e - EE);
    atomicAdd(&offs[d], 1);
}

// ---- hierarchical exclusive scan of offs[NN] (replaces 167us single-WG scan) ----
__global__ void k_scan1(int* __restrict__ offs, int* __restrict__ sums) {
    __shared__ int ts[256];
    int t = threadIdx.x;
    int idx = blockIdx.x * SCB + t * 4;
    int4 v = make_int4(0, 0, 0, 0);
    if (idx + 3 < NN) v = *(const int4*)(offs + idx);
    else {
        if (idx < NN) v.x = offs[idx];
        if (idx + 1 < NN) v.y = offs[idx + 1];
        if (idx + 2 < NN) v.z = offs[idx + 2];
    }
    int s = v.x + v.y + v.z + v.w;
    ts[t] = s;
    __syncthreads();
    for (int o = 1; o < 256; o <<= 1) {
        int u = (t >= o) ? ts[t - o] : 0;
        __syncthreads();
        ts[t] += u;
        __syncthreads();
    }
    int excl = (t > 0) ? ts[t - 1] : 0;
    int4 w;
    w.x = excl; w.y = w.x + v.x; w.z = w.y + v.y; w.w = w.z + v.z;
    if (idx + 3 < NN) *(int4*)(offs + idx) = w;
    else {
        if (idx < NN) offs[idx] = w.x;
        if (idx + 1 < NN) offs[idx + 1] = w.y;
        if (idx + 2 < NN) offs[idx + 2] = w.z;
    }
    if (t == 255) sums[blockIdx.x] = ts[255];
}

__global__ void k_scan2(int* __restrict__ sums) {
    __shared__ int tmp[128];
    int t = threadIdx.x;
    int c = (t < SNB) ? sums[t] : 0;
    tmp[t] = c;
    __syncthreads();
    for (int o = 1; o < 128; o <<= 1) {
        int u = (t >= o) ? tmp[t - o] : 0;
        __syncthreads();
        tmp[t] += u;
        __syncthreads();
    }
    if (t < SNB) sums[t] = tmp[t] - c;  // exclusive
}

__global__ void k_scan3(int* __restrict__ offs, const int* __restrict__ sums) {
    int i = blockIdx.x * blockDim.x + threadIdx.x;
    if (i < NN) offs[i] += sums[i >> 10];
}

// single full-range scatter (NPASS split regressed: write region >> per-XCD L2)
__global__ void k_fill(const int* __restrict__ ei, const float* __restrict__ ea,
                       const float* __restrict__ ea_mean, int* __restrict__ offs,
                       float4* __restrict__ rec) {
    int e = blockIdx.x * blockDim.x + threadIdx.x;
    if (e >= EF) return;
    int d = (e < EE) ? ei[EE + e] : (e - EE);
    int pos = atomicAdd(&offs[d], 1);
    float a[FE];
    int s;
    if (e < EE) {
        s = ei[e];
        const float* r = ea + (size_t)e * FE;
#pragma unroll
        for (int f = 0; f < FE; ++f) a[f] = r[f];
    } else {
        s = e - EE;
#pragma unroll
        for (int f = 0; f < FE; ++f) a[f] = ea_mean[f];
    }
    rec[(size_t)pos * 2]     = make_float4(__int_as_float(s), a[0], a[1], a[2]);
    rec[(size_t)pos * 2 + 1] = make_float4(a[3], a[4], a[5], a[6]);
}

// xl = act(BN(h))@Wl+bl, xr = act(BN(h))@Wr+br, both stored fp16.
template <int FIN, bool BN>
__global__ void k_xform(const float* __restrict__ h,
                        const float* __restrict__ Wl, const float* __restrict__ bl,
                        const float* __restrict__ Wr, const float* __restrict__ br,
                        const double* __restrict__ bn_sum, const double* __restrict__ bn_sumsq,
                        const float* __restrict__ gamma, const float* __restrict__ beta,
                        __half* __restrict__ xl, __half* __restrict__ xr) {
    __shared__ float sWl[FIN * 32], sWr[FIN * 32], sb[64];
    __shared__ float smu[FIN], ssc[FIN], sbe[FIN];
    for (int i = threadIdx.x; i < FIN * 32; i += blockDim.x) { sWl[i] = Wl[i]; sWr[i] = Wr[i]; }
    if (threadIdx.x < 32) { sb[threadIdx.x] = bl[threadIdx.x]; sb[32 + threadIdx.x] = br[threadIdx.x]; }
    if (BN && threadIdx.x < FIN) {
        int f = threadIdx.x;
        double mu = bn_sum[f] * (1.0 / NN);
        double var = bn_sumsq[f] * (1.0 / NN) - mu * mu;
        smu[f] = (float)mu;
        ssc[f] = gamma[f] * (float)(1.0 / sqrt(var + 1e-5));
        sbe[f] = beta[f];
    }
    __syncthreads();
    int idx = blockIdx.x * blockDim.x + threadIdx.x;
    if (idx >= NN * 32) return;
    int n = idx >> 5, c = idx & 31;
    const float* hr = h + (size_t)n * FIN;
    float al = sb[c], ar = sb[32 + c];
#pragma unroll
    for (int f = 0; f < FIN; ++f) {
        float v = hr[f];
        if (BN) {
            v = fmaf(v - smu[f], ssc[f], sbe[f]);
            v = v > 0.f ? v : 0.01f * v;
        }
        al = fmaf(v, sWl[f * 32 + c], al);
        ar = fmaf(v, sWr[f * 32 + c], ar);
    }
    xl[idx] = __float2half(al);
    xr[idx] = __float2half(ar);
}

// GATv2, block-tiled: 32 consecutive dst nodes per block; their contiguous CSR
// slice staged through LDS in coalesced 16KB chunks. 8 lanes per node, 4 ch/lane,
// register accumulation, no-max softmax (logits bounded, shift-invariant).
__global__ __launch_bounds__(256) void k_gat_t(
    const int* __restrict__ offs, const float4* __restrict__ rec,
    const __half* __restrict__ xl, const __half* __restrict__ xr,
    const float* __restrict__ We, const float* __restrict__ att,
    const float* __restrict__ bias, float* __restrict__ hout) {
    __shared__ float4 srec[CR * 2];
    int n0 = blockIdx.x * GNB;
    int g = threadIdx.x >> 3, j = threadIdx.x & 7, c0 = j * 4;
    int node = n0 + g;

    float we[FE][4];
#pragma unroll
    for (int f = 0; f < FE; ++f)
#pragma unroll
        for (int k = 0; k < 4; ++k) we[f][k] = We[f * 32 + c0 + k];
    float at0 = att[c0], at1 = att[c0 + 1], at2 = att[c0 + 2], at3 = att[c0 + 3];

    float2 rawr = *(const float2*)(xr + (size_t)node * 32 + c0);
    float2 q01 = __half22float2(*(const __half2*)&rawr.x);
    float2 q23 = __half22float2(*(const __half2*)&rawr.y);

    int s_g = (node == 0) ? 0 : offs[node - 1];
    int e_g = offs[node];
    int range0 = (n0 == 0) ? 0 : offs[n0 - 1];
    int range1 = offs[n0 + GNB - 1];

    float sm = 0.f, acc0 = 0.f, acc1 = 0.f, acc2 = 0.f, acc3 = 0.f;

    for (int base = range0; base < range1; base += CR) {
        int cnt = range1 - base; if (cnt > CR) cnt = CR;
        __syncthreads();
        for (int i = threadIdx.x; i < cnt * 2; i += 256)
            srec[i] = rec[(size_t)base * 2 + i];
        __syncthreads();
        int lo = s_g > base ? s_g : base;
        int hi = e_g < base + cnt ? e_g : base + cnt;
        for (int p = lo; p < hi; ++p) {
            float4 r0 = srec[(p - base) * 2];
            float4 r1 = srec[(p - base) * 2 + 1];
            int src = __float_as_int(r0.x);
            float2 rawl = *(const float2*)(xl + (size_t)src * 32 + c0);
            float2 l01 = __half22float2(*(const __half2*)&rawl.x);
            float2 l23 = __half22float2(*(const __half2*)&rawl.y);

            float ee0, ee1, ee2, ee3;
            ee0 = r0.y * we[0][0]; ee1 = r0.y * we[0][1]; ee2 = r0.y * we[0][2]; ee3 = r0.y * we[0][3];
            ee0 = fmaf(r0.z, we[1][0], ee0); ee1 = fmaf(r0.z, we[1][1], ee1);
            ee2 = fmaf(r0.z, we[1][2], ee2); ee3 = fmaf(r0.z, we[1][3], ee3);
            ee0 = fmaf(r0.w, we[2][0], ee0); ee1 = fmaf(r0.w, we[2][1], ee1);
            ee2 = fmaf(r0.w, we[2][2], ee2); ee3 = fmaf(r0.w, we[2][3], ee3);
            ee0 = fmaf(r1.x, we[3][0], ee0); ee1 = fmaf(r1.x, we[3][1], ee1);
            ee2 = fmaf(r1.x, we[3][2], ee2); ee3 = fmaf(r1.x, we[3][3], ee3);
            ee0 = fmaf(r1.y, we[4][0], ee0); ee1 = fmaf(r1.y, we[4][1], ee1);
            ee2 = fmaf(r1.y, we[4][2], ee2); ee3 = fmaf(r1.y, we[4][3], ee3);
            ee0 = fmaf(r1.z, we[5][0], ee0); ee1 = fmaf(r1.z, we[5][1], ee1);
            ee2 = fmaf(r1.z, we[5][2], ee2); ee3 = fmaf(r1.z, we[5][3], ee3);
            ee0 = fmaf(r1.w, we[6][0], ee0); ee1 = fmaf(r1.w, we[6][1], ee1);
            ee2 = fmaf(r1.w, we[6][2], ee2); ee3 = fmaf(r1.w, we[6][3], ee3);

            float v0 = l01.x + q01.x + ee0;
            float v1 = l01.y + q01.y + ee1;
            float v2 = l23.x + q23.x + ee2;
            float v3 = l23.y + q23.y + ee3;
            v0 = v0 > 0.f ? v0 : 0.2f * v0;
            v1 = v1 > 0.f ? v1 : 0.2f * v1;
            v2 = v2 > 0.f ? v2 : 0.2f * v2;
            v3 = v3 > 0.f ? v3 : 0.2f * v3;
            float pl = fmaf(v0, at0, fmaf(v1, at1, fmaf(v2, at2, v3 * at3)));
            float L = pl + __shfl_xor(pl, 1, 64);  // per-head logit (pair lanes)
            float ex = __expf(L);
            sm += ex;
            acc0 = fmaf(ex, l01.x, acc0);
            acc1 = fmaf(ex, l01.y, acc1);
            acc2 = fmaf(ex, l23.x, acc2);
            acc3 = fmaf(ex, l23.y, acc3);
        }
    }
    float inv = 1.f / (sm + 1e-16f);
    float4 o;
    o.x = fmaf(acc0, inv, bias[c0 + 0]);
    o.y = fmaf(acc1, inv, bias[c0 + 1]);
    o.z = fmaf(acc2, inv, bias[c0 + 2]);
    o.w = fmaf(acc3, inv, bias[c0 + 3]);
    *(float4*)(hout + (size_t)node * 32 + c0) = o;
}

__global__ void k_bn_stats(const float* __restrict__ h, double* __restrict__ bn_sum,
                           double* __restrict__ bn_sumsq) {
    int c = threadIdx.x & 31;
    int row0 = (blockIdx.x * blockDim.x + threadIdx.x) >> 5;
    int rstride = (gridDim.x * blockDim.x) >> 5;
    float s = 0.f, s2 = 0.f;
    for (int n = row0; n < NN; n += rstride) {
        float v = h[(size_t)n * 32 + c];
        s += v;
        s2 = fmaf(v, v, s2);
    }
    s += __shfl_down(s, 32, 64);
    s2 += __shfl_down(s2, 32, 64);
    __shared__ float ls[4][32], ls2[4][32];
    int w = threadIdx.x >> 6;
    if ((threadIdx.x & 63) < 32) { ls[w][c] = s; ls2[w][c] = s2; }
    __syncthreads();
    if (threadIdx.x < 32) {
        float tsum = 0.f, tsq = 0.f;
        for (int i = 0; i < 4; ++i) { tsum += ls[i][threadIdx.x]; tsq += ls2[i][threadIdx.x]; }
        atomicAdd(&bn_sum[threadIdx.x], (double)tsum);
        atomicAdd(&bn_sumsq[threadIdx.x], (double)tsq);
    }
}

// wend = Wreg@Wend, c0 = breg.Wend + bend  (linear∘linear collapse)
__global__ void k_wend(const float* __restrict__ Wreg, const float* __restrict__ breg,
                       const float* __restrict__ Wend, const float* __restrict__ bend,
                       float* __restrict__ wend, float* __restrict__ c0v) {
    int t = threadIdx.x;
    if (t < 32) {
        float s = 0.f;
        for (int k = 0; k < 500; ++k) s = fmaf(Wreg[t * 500 + k], Wend[k], s);
        wend[t] = s;
    } else if (t == 32) {
        float s = 0.f;
        for (int k = 0; k < 500; ++k) s = fmaf(breg[k], Wend[k], s);
        *c0v = s + bend[0];
    }
}

__global__ void k_out(const float* __restrict__ h, const float* __restrict__ wend,
                      const float* __restrict__ c0v, float* __restrict__ out) {
    int n = blockIdx.x * blockDim.x + threadIdx.x;
    if (n >= NN) return;
    const float* r = h + (size_t)n * 32;
    float s = *c0v;
#pragma unroll
    for (int c = 0; c < 32; ++c) {
        float v = r[c];
        v = v > 0.f ? v : 0.01f * v;
        s = fmaf(v, wend[c], s);
    }
    out[n] = s;
}

extern "C" void kernel_launch(void* const* d_in, const int* in_sizes, int n_in,
                              void* d_out, int out_size, void* d_ws, size_t ws_size,
                              hipStream_t stream) {
    (void)in_sizes; (void)n_in; (void)out_size; (void)ws_size;
    const float* x    = (const float*)d_in[0];
    const int*   ei   = (const int*)d_in[1];
    const float* ea   = (const float*)d_in[2];
    const float* Wl1  = (const float*)d_in[3];
    const float* bl1  = (const float*)d_in[4];
    const float* Wr1  = (const float*)d_in[5];
    const float* br1  = (const float*)d_in[6];
    const float* We1  = (const float*)d_in[7];
    const float* att1 = (const float*)d_in[8];
    const float* b1   = (const float*)d_in[9];
    const float* Wl2  = (const float*)d_in[10];
    const float* bl2  = (const float*)d_in[11];
    const float* Wr2  = (const float*)d_in[12];
    const float* br2  = (const float*)d_in[13];
    const float* We2  = (const float*)d_in[14];
    const float* att2 = (const float*)d_in[15];
    const float* b2   = (const float*)d_in[16];
    const float* gamma= (const float*)d_in[17];
    const float* beta = (const float*)d_in[18];
    const float* Wreg = (const float*)d_in[19];
    const float* breg = (const float*)d_in[20];
    const float* Wend = (const float*)d_in[21];
    const float* bend = (const float*)d_in[22];
    float* out = (float*)d_out;

    char* w = (char*)d_ws;
    double* ea_sum   = (double*)(w + 0);
    double* bn_sum   = (double*)(w + 64);
    double* bn_sumsq = (double*)(w + 320);
    float*  ea_mean  = (float*)(w + 576);
    float*  wend     = (float*)(w + 608);
    float*  c0v      = (float*)(w + 736);
    int*    ssum     = (int*)(w + 1024);  // 128 ints
    size_t o = 2048;
    int* offs = (int*)(w + o); o += ((size_t)NN * 4 + 255) & ~(size_t)255;
    __half* xl = (__half*)(w + o); o += ((size_t)NN * 32 * 2 + 255) & ~(size_t)255;
    __half* xr = (__half*)(w + o); o += ((size_t)NN * 32 * 2 + 255) & ~(size_t)255;
    float* hb = (float*)(w + o); o += (size_t)NN * 32 * 4;
    float4* rec = (float4*)(w + o); o += (size_t)EF * 32;

    hipMemsetAsync(w, 0, 2048, stream);
    hipMemsetAsync(offs, 0, (size_t)NN * 4, stream);

    const int ebl = (EF + 255) / 256;
    k_ea_sum<<<256, 256, 0, stream>>>(ea, ea_sum);
    k_ea_mean<<<1, 64, 0, stream>>>(ea_sum, ea_mean);
    k_degree<<<ebl, 256, 0, stream>>>(ei, offs);
    k_scan1<<<SNB, 256, 0, stream>>>(offs, ssum);
    k_scan2<<<1, 128, 0, stream>>>(ssum);
    k_scan3<<<(NN + 255) / 256, 256, 0, stream>>>(offs, ssum);
    k_fill<<<ebl, 256, 0, stream>>>(ei, ea, ea_mean, offs, rec);
    k_wend<<<1, 64, 0, stream>>>(Wreg, breg, Wend, bend, wend, c0v);

    const int xbl = (NN * 32 + 255) / 256;
    const int gbl = NN / GNB;  // 3125, exact

    // layer 1 (no BN on raw input x)
    k_xform<2, false><<<xbl, 256, 0, stream>>>(x, Wl1, bl1, Wr1, br1,
                                               bn_sum, bn_sumsq, gamma, beta, xl, xr);
    k_gat_t<<<gbl, 256, 0, stream>>>(offs, rec, xl, xr, We1, att1, b1, hb);

    // 2x (BN-stats -> fused BN+lrelu+xform -> layer2 GAT)
    for (int it = 0; it < 2; ++it) {
        hipMemsetAsync(w + 64, 0, 512, stream);
        k_bn_stats<<<256, 256, 0, stream>>>(hb, bn_sum, bn_sumsq);
        k_xform<32, true><<<xbl, 256, 0, stream>>>(hb, Wl2, bl2, Wr2, br2,
                                                   bn_sum, bn_sumsq, gamma, beta, xl, xr);
        k_gat_t<<<gbl, 256, 0, stream>>>(offs, rec, xl, xr, We2, att2, b2, hb);
    }

    k_out<<<(NN + 255) / 256, 256, 0, stream>>>(hb, wend, c0v, out);
}